// Round 8
// baseline (229.352 us; speedup 1.0000x reference)
//
#include <hip/hip_runtime.h>
#include <math.h>

#define BB 2048
#define LL 120
#define WE_ 50
#define PE_ 5
#define DD 60
#define FF 230
#define KK 3
#define RR 53

#define NKT 6             // K = 192 = 6 x 32
#define NNT 15            // N = 240 = 15 x 16
#define NPAD 240
#define EMB_ELEMS 7936    // >= 127*60 + 180 = 7800; row 0, rows >=121, tail zeroed

typedef __attribute__((ext_vector_type(8))) short short8_t;
typedef __attribute__((ext_vector_type(4))) short short4_t;
typedef __attribute__((ext_vector_type(4))) float float4_t;

__device__ __forceinline__ unsigned short f2bf(float x) {
    unsigned u = __builtin_bit_cast(unsigned, x);
    unsigned r = (u + 0x7fffu + ((u >> 16) & 1u)) >> 16;
    return (unsigned short)r;
}

__device__ __forceinline__ float tanh_fast(float x) {
    float t = __expf(2.0f * x);
    return 1.0f - 2.0f * __builtin_amdgcn_rcpf(t + 1.0f);
}

// ---- prep: pack conv_w (f32 [230][180]) into bf16 MFMA B-fragment-linear layout ----
// bp[(((nt*6 + kt)*64) + lane)*8 + j] = W[f = nt*16+(lane&15)][klin = kt*32+(lane>>4)*8+j]
__global__ __launch_bounds__(256) void pcnn_prep_b(const float* __restrict__ convw,
                                                   unsigned short* __restrict__ bp) {
    int idx = blockIdx.x * 256 + threadIdx.x;
    if (idx >= NNT * NKT * 64 * 8) return;
    int j    = idx & 7;
    int lane = (idx >> 3) & 63;
    int t    = idx >> 9;
    int kt   = t % NKT;
    int nt   = t / NKT;
    int f    = nt * 16 + (lane & 15);
    int klin = kt * 32 + (lane >> 4) * 8 + j;
    float v = (f < FF && klin < KK * DD) ? convw[f * (KK * DD) + klin] : 0.0f;
    bp[idx] = f2bf(v);
}

__global__ __launch_bounds__(256) void pcnn_mfma(
    const int* __restrict__ sent, const int* __restrict__ pf,
    const int* __restrict__ epos,
    const float* __restrict__ Wword, const float* __restrict__ Wpos1,
    const float* __restrict__ Wpos2,
    const unsigned short* __restrict__ bp, const float* __restrict__ convb,
    const float* __restrict__ linw, const float* __restrict__ linb,
    float* __restrict__ out)
{
    // emb is dead after A-frag register loads -> overlay partial/feats on it
    __shared__ __align__(16) union SM {
        unsigned short emb[EMB_ELEMS];            // 15872 B
        float pool[4 * NPAD * 3 + NPAD * 3];      // partial (2880 f) + feats (720 f) = 14400 B
    } sm;
    float* const partial = sm.pool;               // [wid][f][s]
    float* const feats   = sm.pool + 4 * NPAD * 3;

    const int b    = blockIdx.x;
    const int tid  = threadIdx.x;
    const int wid  = tid >> 6;
    const int lane = tid & 63;

    const int pool0 = epos[b * 2 + 0] + 1;
    const int pool1 = epos[b * 2 + 1] + 1;

    // ---- zero pad regions as dwords: [0,60) shorts and [7260, 7936) shorts ----
    {
        unsigned* e32 = (unsigned*)sm.emb;
        for (int i = tid; i < 30 + 338; i += 256) {
            int idx = (i < 30) ? i : (3630 + (i - 30));   // dword units
            e32[idx] = 0u;
        }
    }
    // ---- word embeddings as float2 -> packed bf16 dword: emb[(l+1)*60 + 2c], c<25 ----
    for (int i = tid; i < LL * 25; i += 256) {
        int l = i / 25;
        int c = i - l * 25;
        int w = sent[b * LL + l];
        float2 v = *(const float2*)(Wword + w * WE_ + 2 * c);
        unsigned pk = (unsigned)f2bf(v.x) | ((unsigned)f2bf(v.y) << 16);
        *(unsigned*)(sm.emb + (l + 1) * DD + 2 * c) = pk;
    }
    // ---- position embeddings: emb[(l+1)*60 + 50..59] ----
    for (int i = tid; i < LL * 2 * PE_; i += 256) {
        int l = i / (2 * PE_);
        int d = i - l * (2 * PE_);
        if (d < PE_) {
            int p = pf[b * 2 * LL + l];
            sm.emb[(l + 1) * DD + WE_ + d] = f2bf(Wpos1[p * PE_ + d]);
        } else {
            int q = pf[b * 2 * LL + LL + l];
            sm.emb[(l + 1) * DD + WE_ + d] = f2bf(Wpos2[q * PE_ + (d - PE_)]);
        }
    }
    __syncthreads();

    // ---- A fragments: wave owns m-tiles {2*wid, 2*wid+1}; im2col row l = emb[l*60 .. +180) ----
    short8_t afrag[2][NKT];
    #pragma unroll
    for (int tm2 = 0; tm2 < 2; ++tm2) {
        int l = (2 * wid + tm2) * 16 + (lane & 15);
        #pragma unroll
        for (int kt = 0; kt < NKT; ++kt) {
            int e = l * DD + kt * 32 + (lane >> 4) * 8;   // 8B-aligned element offset
            short4_t lo = *(const short4_t*)(sm.emb + e);
            short4_t hi = *(const short4_t*)(sm.emb + e + 4);
            short8_t f8;
            f8[0] = lo[0]; f8[1] = lo[1]; f8[2] = lo[2]; f8[3] = lo[3];
            f8[4] = hi[0]; f8[5] = hi[1]; f8[6] = hi[2]; f8[7] = hi[3];
            afrag[tm2][kt] = f8;
        }
    }
    __syncthreads();   // emb now dead; pool overlay becomes live

    // ---- per-(tm2,r) segment masks {0,-INF}, nt-invariant ----
    const int qrow = (lane >> 4) * 4;
    float msk[2][4][3];
    #pragma unroll
    for (int tm2 = 0; tm2 < 2; ++tm2) {
        #pragma unroll
        for (int r = 0; r < 4; ++r) {
            int l = wid * 32 + tm2 * 16 + qrow + r;
            bool valid = l < LL;
            int seg = (l >= pool0) + (l >= pool1);
            msk[tm2][r][0] = (valid && seg == 0) ? 0.0f : -INFINITY;
            msk[tm2][r][1] = (valid && seg == 1) ? 0.0f : -INFINITY;
            msk[tm2][r][2] = (valid && seg == 2) ? 0.0f : -INFINITY;
        }
    }

    // ---- main loop over n-tiles: MFMA + raw-acc segment max (tanh deferred) ----
    #pragma unroll 3
    for (int nt = 0; nt < NNT; ++nt) {
        const short8_t* bpv = (const short8_t*)(bp) + (nt * NKT) * 64;
        short8_t bfrag[NKT];
        #pragma unroll
        for (int kt = 0; kt < NKT; ++kt) bfrag[kt] = bpv[kt * 64 + lane];

        float4_t acc0 = {0.f, 0.f, 0.f, 0.f};
        float4_t acc1 = {0.f, 0.f, 0.f, 0.f};
        #pragma unroll
        for (int kt = 0; kt < NKT; ++kt) {
            acc0 = __builtin_amdgcn_mfma_f32_16x16x32_bf16(afrag[0][kt], bfrag[kt], acc0, 0, 0, 0);
            acc1 = __builtin_amdgcn_mfma_f32_16x16x32_bf16(afrag[1][kt], bfrag[kt], acc1, 0, 0, 0);
        }

        float mx0 = -INFINITY, mx1 = -INFINITY, mx2 = -INFINITY;
        #pragma unroll
        for (int tm2 = 0; tm2 < 2; ++tm2) {
            #pragma unroll
            for (int r = 0; r < 4; ++r) {
                float v = tm2 ? acc1[r] : acc0[r];
                mx0 = fmaxf(mx0, v + msk[tm2][r][0]);
                mx1 = fmaxf(mx1, v + msk[tm2][r][1]);
                mx2 = fmaxf(mx2, v + msk[tm2][r][2]);
            }
        }
        mx0 = fmaxf(mx0, __shfl_xor(mx0, 16)); mx0 = fmaxf(mx0, __shfl_xor(mx0, 32));
        mx1 = fmaxf(mx1, __shfl_xor(mx1, 16)); mx1 = fmaxf(mx1, __shfl_xor(mx1, 32));
        mx2 = fmaxf(mx2, __shfl_xor(mx2, 16)); mx2 = fmaxf(mx2, __shfl_xor(mx2, 32));
        if (lane < 16) {
            partial[(wid * NPAD + nt * 16 + lane) * 3 + 0] = mx0;
            partial[(wid * NPAD + nt * 16 + lane) * 3 + 1] = mx1;
            partial[(wid * NPAD + nt * 16 + lane) * 3 + 2] = mx2;
        }
    }
    __syncthreads();

    // ---- combine wave partials + deferred bias + tanh (only 690 values) ----
    for (int i = tid; i < FF * 3; i += 256) {
        float m = partial[i];
        m = fmaxf(m, partial[NPAD * 3 + i]);
        m = fmaxf(m, partial[2 * NPAD * 3 + i]);
        m = fmaxf(m, partial[3 * NPAD * 3 + i]);
        int f = i / 3;
        feats[i] = tanh_fast(m + convb[f]);
    }
    __syncthreads();

    // ---- linear epilogue: out[b,r] = feats[0:690] . linw[r,:] + linb[r] ----
    if (tid < 4 * RR) {  // 212 threads: r = tid>>2, p = tid&3
        int r = tid >> 2;
        int p = tid & 3;
        float acc = 0.0f;
        for (int i = p; i < 3 * FF; i += 4) acc += feats[i] * linw[r * (3 * FF) + i];
        acc += __shfl_xor(acc, 1);
        acc += __shfl_xor(acc, 2);
        if (p == 0) out[b * RR + r] = acc + linb[r];
    }
}

extern "C" void kernel_launch(void* const* d_in, const int* in_sizes, int n_in,
                              void* d_out, int out_size, void* d_ws, size_t ws_size,
                              hipStream_t stream) {
    const int*   sent  = (const int*)d_in[0];
    const int*   pf    = (const int*)d_in[1];
    const int*   epos  = (const int*)d_in[2];
    const float* Wword = (const float*)d_in[3];
    const float* Wpos1 = (const float*)d_in[4];
    const float* Wpos2 = (const float*)d_in[5];
    const float* convw = (const float*)d_in[6];
    const float* convb = (const float*)d_in[7];
    const float* linw  = (const float*)d_in[8];
    const float* linb  = (const float*)d_in[9];
    float* out = (float*)d_out;
    unsigned short* bp = (unsigned short*)d_ws;   // 46080 bf16 = 92160 B

    int nprep = (NNT * NKT * 64 * 8 + 255) / 256;
    pcnn_prep_b<<<nprep, 256, 0, stream>>>(convw, bp);
    pcnn_mfma<<<BB, 256, 0, stream>>>(sent, pf, epos, Wword, Wpos1, Wpos2,
                                      bp, convb, linw, linb, out);
}

// Round 9
// 174.520 us; speedup vs baseline: 1.3142x; 1.3142x over previous
//
#include <hip/hip_runtime.h>
#include <math.h>

#define BB 2048
#define LL 120
#define WE_ 50
#define PE_ 5
#define DD 60
#define FF 230
#define KK 3
#define RR 53

#define NKT 6             // K = 192 = 6 x 32
#define NNT 15            // N = 240 = 15 x 16
#define NPAD 240
#define EMB_ELEMS 7936    // row r at element r*60+4; rows 1..120 live, row 0 & >=121 zero

// workspace layout (bytes)
#define WS_BP    0                        // 46080 bf16 = 92160 B
#define WS_LT    92160                    // linw_t f32 [690][56] = 154560 B
#define WS_EMBG  246784                   // 16-aligned; bf16 [2048][120][60] = 29491200 B

typedef __attribute__((ext_vector_type(8))) short short8_t;
typedef __attribute__((ext_vector_type(4))) short short4_t;
typedef __attribute__((ext_vector_type(4))) float float4_t;

__device__ __forceinline__ unsigned f2bf(float x) {
    unsigned u = __builtin_bit_cast(unsigned, x);
    return (u + 0x7fffu + ((u >> 16) & 1u)) >> 16;
}

__device__ __forceinline__ float tanh_fast(float x) {
    float t = __expf(2.0f * x);
    return 1.0f - 2.0f * __builtin_amdgcn_rcpf(t + 1.0f);
}

// ---- prep 1: pack conv_w into bf16 MFMA B-fragment-linear layout ----
__global__ __launch_bounds__(256) void pcnn_prep_b(const float* __restrict__ convw,
                                                   unsigned short* __restrict__ bp) {
    int idx = blockIdx.x * 256 + threadIdx.x;
    if (idx >= NNT * NKT * 64 * 8) return;
    int j    = idx & 7;
    int lane = (idx >> 3) & 63;
    int t    = idx >> 9;
    int kt   = t % NKT;
    int nt   = t / NKT;
    int f    = nt * 16 + (lane & 15);
    int klin = kt * 32 + (lane >> 4) * 8 + j;
    float v = (f < FF && klin < KK * DD) ? convw[f * (KK * DD) + klin] : 0.0f;
    bp[idx] = (unsigned short)f2bf(v);
}

// ---- prep 2: transpose lin_w [53][690] -> linw_t [690][56] (pad rows 53..55 = 0) ----
__global__ __launch_bounds__(256) void pcnn_prep_lt(const float* __restrict__ linw,
                                                    float* __restrict__ lt) {
    int idx = blockIdx.x * 256 + threadIdx.x;
    if (idx >= 690 * 56) return;
    int i = idx / 56;
    int r = idx - i * 56;
    lt[idx] = (r < RR) ? linw[r * (3 * FF) + i] : 0.0f;
}

// ---- gather: one thread per output dword of emb_g[b][l][0..29] ----
__global__ __launch_bounds__(256) void pcnn_gather(
    const int* __restrict__ sent, const int* __restrict__ pf,
    const float* __restrict__ Wword, const float* __restrict__ Wpos1,
    const float* __restrict__ Wpos2, unsigned* __restrict__ embg32)
{
    int idx = blockIdx.x * 256 + threadIdx.x;      // < 2048*120*30 = 7372800
    if (idx >= BB * LL * 30) return;
    int c  = idx % 30;
    int lc = idx / 30;
    int l  = lc % LL;
    int b  = lc / LL;
    unsigned pk;
    if (c < 25) {
        int w = sent[b * LL + l];
        float2 v = *(const float2*)(Wword + w * WE_ + 2 * c);
        pk = f2bf(v.x) | (f2bf(v.y) << 16);
    } else {
        int p = pf[b * 2 * LL + l];
        int q = pf[b * 2 * LL + LL + l];
        int j0 = (c - 25) * 2, j1 = j0 + 1;
        float f0 = (j0 < PE_) ? Wpos1[p * PE_ + j0] : Wpos2[q * PE_ + j0 - PE_];
        float f1 = (j1 < PE_) ? Wpos1[p * PE_ + j1] : Wpos2[q * PE_ + j1 - PE_];
        pk = f2bf(f0) | (f2bf(f1) << 16);
    }
    embg32[idx] = pk;   // dest dword index == idx: fully coalesced
}

__global__ __launch_bounds__(256) void pcnn_mfma(
    const int* __restrict__ epos,
    const unsigned short* __restrict__ embg,      // [2048][120][60] bf16
    const unsigned short* __restrict__ bp, const float* __restrict__ convb,
    const float* __restrict__ linw_t, const float* __restrict__ linb,
    float* __restrict__ out)
{
    // emb dead after A-frag loads -> overlay pool on it
    __shared__ __align__(16) union SM {
        unsigned short emb[EMB_ELEMS];                    // 15872 B; row r at elem r*60+4
        float pool[4 * NPAD * 3 + NPAD * 3 + 4 * 56];     // partial + feats + part2 = 15296 B
    } sm;
    float* const partial = sm.pool;                       // [wid][f][s]
    float* const feats   = sm.pool + 4 * NPAD * 3;
    float* const part2   = sm.pool + 4 * NPAD * 3 + NPAD * 3;

    const int b    = blockIdx.x;
    const int tid  = threadIdx.x;
    const int wid  = tid >> 6;
    const int lane = tid & 63;

    const int pool0 = epos[b * 2 + 0] + 1;
    const int pool1 = epos[b * 2 + 1] + 1;

    // ---- zero pads as dwords: elems [0,64) -> dwords [0,32); elems [7264,7936) -> dwords [3632,3968) ----
    {
        unsigned* e32 = (unsigned*)sm.emb;
        for (int i = tid; i < 32 + 336; i += 256) {
            int d = (i < 32) ? i : (3600 + i);
            e32[d] = 0u;
        }
    }
    // ---- stage rows 1..120 from emb_g: 900 x 16B chunks, coalesced, 16B-aligned both sides ----
    {
        const unsigned short* eb = embg + (size_t)b * (LL * DD);
        #pragma unroll
        for (int k = 0; k < 4; ++k) {
            int c = tid + k * 256;
            if (c < 900) {
                float4 v = *(const float4*)(eb + c * 8);
                *(float4*)((char*)sm.emb + 128 + c * 16) = v;   // row1 starts at elem 64 = byte 128
            }
        }
    }
    __syncthreads();

    // ---- A fragments: wave owns m-tiles {2*wid, 2*wid+1}; im2col row l = emb[l*60+4 .. +180) ----
    short8_t afrag[2][NKT];
    #pragma unroll
    for (int tm2 = 0; tm2 < 2; ++tm2) {
        int l = (2 * wid + tm2) * 16 + (lane & 15);
        #pragma unroll
        for (int kt = 0; kt < NKT; ++kt) {
            int e = l * DD + 4 + kt * 32 + (lane >> 4) * 8;   // 8B-aligned
            short4_t lo = *(const short4_t*)(sm.emb + e);
            short4_t hi = *(const short4_t*)(sm.emb + e + 4);
            short8_t f8;
            f8[0] = lo[0]; f8[1] = lo[1]; f8[2] = lo[2]; f8[3] = lo[3];
            f8[4] = hi[0]; f8[5] = hi[1]; f8[6] = hi[2]; f8[7] = hi[3];
            afrag[tm2][kt] = f8;
        }
    }
    __syncthreads();   // emb dead; pool overlay live

    // ---- per-(tm2,r) segment masks {0,-INF}, nt-invariant ----
    const int qrow = (lane >> 4) * 4;
    float msk[2][4][3];
    #pragma unroll
    for (int tm2 = 0; tm2 < 2; ++tm2) {
        #pragma unroll
        for (int r = 0; r < 4; ++r) {
            int l = wid * 32 + tm2 * 16 + qrow + r;
            bool valid = l < LL;
            int seg = (l >= pool0) + (l >= pool1);
            msk[tm2][r][0] = (valid && seg == 0) ? 0.0f : -INFINITY;
            msk[tm2][r][1] = (valid && seg == 1) ? 0.0f : -INFINITY;
            msk[tm2][r][2] = (valid && seg == 2) ? 0.0f : -INFINITY;
        }
    }

    // ---- main loop over n-tiles ----
    #pragma unroll 3
    for (int nt = 0; nt < NNT; ++nt) {
        const short8_t* bpv = (const short8_t*)(bp) + (nt * NKT) * 64;
        short8_t bfrag[NKT];
        #pragma unroll
        for (int kt = 0; kt < NKT; ++kt) bfrag[kt] = bpv[kt * 64 + lane];

        float4_t acc0 = {0.f, 0.f, 0.f, 0.f};
        float4_t acc1 = {0.f, 0.f, 0.f, 0.f};
        #pragma unroll
        for (int kt = 0; kt < NKT; ++kt) {
            acc0 = __builtin_amdgcn_mfma_f32_16x16x32_bf16(afrag[0][kt], bfrag[kt], acc0, 0, 0, 0);
            acc1 = __builtin_amdgcn_mfma_f32_16x16x32_bf16(afrag[1][kt], bfrag[kt], acc1, 0, 0, 0);
        }

        float mx0 = -INFINITY, mx1 = -INFINITY, mx2 = -INFINITY;
        #pragma unroll
        for (int tm2 = 0; tm2 < 2; ++tm2) {
            #pragma unroll
            for (int r = 0; r < 4; ++r) {
                float v = tm2 ? acc1[r] : acc0[r];
                mx0 = fmaxf(mx0, v + msk[tm2][r][0]);
                mx1 = fmaxf(mx1, v + msk[tm2][r][1]);
                mx2 = fmaxf(mx2, v + msk[tm2][r][2]);
            }
        }
        mx0 = fmaxf(mx0, __shfl_xor(mx0, 16)); mx0 = fmaxf(mx0, __shfl_xor(mx0, 32));
        mx1 = fmaxf(mx1, __shfl_xor(mx1, 16)); mx1 = fmaxf(mx1, __shfl_xor(mx1, 32));
        mx2 = fmaxf(mx2, __shfl_xor(mx2, 16)); mx2 = fmaxf(mx2, __shfl_xor(mx2, 32));
        if (lane < 16) {
            partial[(wid * NPAD + nt * 16 + lane) * 3 + 0] = mx0;
            partial[(wid * NPAD + nt * 16 + lane) * 3 + 1] = mx1;
            partial[(wid * NPAD + nt * 16 + lane) * 3 + 2] = mx2;
        }
    }
    __syncthreads();

    // ---- combine wave partials + deferred bias + tanh (690 values) ----
    for (int i = tid; i < FF * 3; i += 256) {
        float m = partial[i];
        m = fmaxf(m, partial[NPAD * 3 + i]);
        m = fmaxf(m, partial[2 * NPAD * 3 + i]);
        m = fmaxf(m, partial[3 * NPAD * 3 + i]);
        int f = i / 3;
        feats[i] = tanh_fast(m + convb[f]);
    }
    __syncthreads();

    // ---- GEMV epilogue: wave w covers i in [690w/4, 690(w+1)/4); lane r reads linw_t coalesced ----
    {
        int i0 = (690 * wid) >> 2;
        int i1 = (690 * (wid + 1)) >> 2;
        float acc = 0.0f;
        if (lane < 56) {
            #pragma unroll 4
            for (int i = i0; i < i1; ++i)
                acc += feats[i] * linw_t[i * 56 + lane];
            part2[wid * 56 + lane] = acc;
        }
    }
    __syncthreads();
    if (tid < RR) {
        float s = part2[tid] + part2[56 + tid] + part2[112 + tid] + part2[168 + tid];
        out[b * RR + tid] = s + linb[tid];
    }
}

extern "C" void kernel_launch(void* const* d_in, const int* in_sizes, int n_in,
                              void* d_out, int out_size, void* d_ws, size_t ws_size,
                              hipStream_t stream) {
    const int*   sent  = (const int*)d_in[0];
    const int*   pf    = (const int*)d_in[1];
    const int*   epos  = (const int*)d_in[2];
    const float* Wword = (const float*)d_in[3];
    const float* Wpos1 = (const float*)d_in[4];
    const float* Wpos2 = (const float*)d_in[5];
    const float* convw = (const float*)d_in[6];
    const float* convb = (const float*)d_in[7];
    const float* linw  = (const float*)d_in[8];
    const float* linb  = (const float*)d_in[9];
    float* out = (float*)d_out;

    char* ws = (char*)d_ws;
    unsigned short* bp     = (unsigned short*)(ws + WS_BP);
    float*          linw_t = (float*)(ws + WS_LT);
    unsigned short* embg   = (unsigned short*)(ws + WS_EMBG);

    int nprep = (NNT * NKT * 64 * 8 + 255) / 256;
    pcnn_prep_b<<<nprep, 256, 0, stream>>>(convw, bp);
    pcnn_prep_lt<<<(690 * 56 + 255) / 256, 256, 0, stream>>>(linw, linw_t);
    pcnn_gather<<<(BB * LL * 30) / 256, 256, 0, stream>>>(sent, pf, Wword, Wpos1, Wpos2,
                                                          (unsigned*)embg);
    pcnn_mfma<<<BB, 256, 0, stream>>>(epos, embg, bp, convb, linw_t, linb, out);
}

// Round 11
// 166.469 us; speedup vs baseline: 1.3777x; 1.0484x over previous
//
#include <hip/hip_runtime.h>
#include <math.h>

#define BB 2048
#define LL 120
#define WE_ 50
#define PE_ 5
#define DD 60
#define FF 230
#define KK 3
#define RR 53

#define NKT 6             // K = 192 = 6 x 32
#define NNT 15            // N = 240 = 15 x 16
#define NPAD 240
#define EMB_ELEMS 7936    // LDS row r at elem r*60+4; rows 1..120 live, row 0 & >=121 zero

// workspace layout (bytes)
#define WS_BP    0                        // 46080 bf16 = 92160 B
#define WS_LT    92160                    // linw_t f32 [690][56] = 154560 B
#define WS_EMBG  246784                   // 16-aligned; bf16 [2048][120][60] = 29491200 B

#define ACC_BIAS 16.0f                    // |conv_raw| < 0.05 << 16 -> key always positive

typedef __attribute__((ext_vector_type(8))) short short8_t;
typedef __attribute__((ext_vector_type(4))) short short4_t;
typedef __attribute__((ext_vector_type(4))) float float4_t;

__device__ __forceinline__ unsigned f2bf(float x) {
    unsigned u = __builtin_bit_cast(unsigned, x);
    return (u + 0x7fffu + ((u >> 16) & 1u)) >> 16;
}

__device__ __forceinline__ float tanh_fast(float x) {
    float t = __expf(2.0f * x);
    return 1.0f - 2.0f * __builtin_amdgcn_rcpf(t + 1.0f);
}

// ---- prep 1: pack conv_w into bf16 MFMA B-fragment-linear layout (r9 verbatim) ----
__global__ __launch_bounds__(256) void pcnn_prep_b(const float* __restrict__ convw,
                                                   unsigned short* __restrict__ bp) {
    int idx = blockIdx.x * 256 + threadIdx.x;
    if (idx >= NNT * NKT * 64 * 8) return;
    int j    = idx & 7;
    int lane = (idx >> 3) & 63;
    int t    = idx >> 9;
    int kt   = t % NKT;
    int nt   = t / NKT;
    int f    = nt * 16 + (lane & 15);
    int klin = kt * 32 + (lane >> 4) * 8 + j;
    float v = (f < FF && klin < KK * DD) ? convw[f * (KK * DD) + klin] : 0.0f;
    bp[idx] = (unsigned short)f2bf(v);
}

// ---- prep 2: transpose lin_w [53][690] -> linw_t [690][56] (r9 verbatim) ----
__global__ __launch_bounds__(256) void pcnn_prep_lt(const float* __restrict__ linw,
                                                    float* __restrict__ lt) {
    int idx = blockIdx.x * 256 + threadIdx.x;
    if (idx >= 690 * 56) return;
    int i = idx / 56;
    int r = idx - i * 56;
    lt[idx] = (r < RR) ? linw[r * (3 * FF) + i] : 0.0f;
}

// ---- gather: one thread per output dword of emb_g[b][l][0..29] (r9 verbatim) ----
__global__ __launch_bounds__(256) void pcnn_gather(
    const int* __restrict__ sent, const int* __restrict__ pf,
    const float* __restrict__ Wword, const float* __restrict__ Wpos1,
    const float* __restrict__ Wpos2, unsigned* __restrict__ embg32)
{
    int idx = blockIdx.x * 256 + threadIdx.x;      // < 2048*120*30 = 7372800
    if (idx >= BB * LL * 30) return;
    int c  = idx % 30;
    int lc = idx / 30;
    int l  = lc % LL;
    int b  = lc / LL;
    unsigned pk;
    if (c < 25) {
        int w = sent[b * LL + l];
        float2 v = *(const float2*)(Wword + w * WE_ + 2 * c);
        pk = f2bf(v.x) | (f2bf(v.y) << 16);
    } else {
        int p = pf[b * 2 * LL + l];
        int q = pf[b * 2 * LL + LL + l];
        int j0 = (c - 25) * 2, j1 = j0 + 1;
        float f0 = (j0 < PE_) ? Wpos1[p * PE_ + j0] : Wpos2[q * PE_ + j0 - PE_];
        float f1 = (j1 < PE_) ? Wpos1[p * PE_ + j1] : Wpos2[q * PE_ + j1 - PE_];
        pk = f2bf(f0) | (f2bf(f1) << 16);
    }
    embg32[idx] = pk;   // dest dword index == idx: fully coalesced
}

__global__ __launch_bounds__(256) void pcnn_mfma(
    const int* __restrict__ epos,
    const unsigned short* __restrict__ embg,      // [2048][120][60] bf16
    const unsigned short* __restrict__ bp, const float* __restrict__ convb,
    const float* __restrict__ linw_t, const float* __restrict__ linb,
    float* __restrict__ out)
{
    // emb dead after A-frag loads -> overlay pool on it (r9 union layout)
    __shared__ __align__(16) union SM {
        unsigned short emb[EMB_ELEMS];                    // 15872 B; row r at elem r*60+4
        float pool[4 * NPAD * 3 + NPAD * 3 + 4 * 56];     // keys | feats | part2
    } sm;
    unsigned* const keys  = (unsigned*)sm.pool;           // [NPAD*3] bit-keys of (conv+16)
    float* const feats    = sm.pool + 4 * NPAD * 3;
    float* const part2    = sm.pool + 4 * NPAD * 3 + NPAD * 3;

    const int b    = blockIdx.x;
    const int tid  = threadIdx.x;
    const int wid  = tid >> 6;
    const int lane = tid & 63;

    const int pool0 = epos[b * 2 + 0] + 1;
    const int pool1 = epos[b * 2 + 1] + 1;

    // ---- zero pads as dwords: elems [0,64) -> dwords [0,32); elems [7264,7936) -> dwords [3632,3968) ----
    {
        unsigned* e32 = (unsigned*)sm.emb;
        for (int i = tid; i < 32 + 336; i += 256) {
            int d = (i < 32) ? i : (3600 + i);
            e32[d] = 0u;
        }
    }
    // ---- stage rows 1..120 from emb_g: 900 x 16B chunks, coalesced, 16B-aligned both sides ----
    {
        const unsigned short* eb = embg + (size_t)b * (LL * DD);
        #pragma unroll
        for (int k = 0; k < 4; ++k) {
            int c = tid + k * 256;
            if (c < 900) {
                float4 v = *(const float4*)(eb + c * 8);
                *(float4*)((char*)sm.emb + 128 + c * 16) = v;   // row1 starts at elem 64 = byte 128
            }
        }
    }
    __syncthreads();

    // ---- A fragments: wave owns m-tiles {2*wid, 2*wid+1}; im2col row l = emb[l*60+4 .. +180) ----
    short8_t afrag[2][NKT];
    #pragma unroll
    for (int tm2 = 0; tm2 < 2; ++tm2) {
        int l = (2 * wid + tm2) * 16 + (lane & 15);
        #pragma unroll
        for (int kt = 0; kt < NKT; ++kt) {
            int e = l * DD + 4 + kt * 32 + (lane >> 4) * 8;   // 8B-aligned
            short4_t lo = *(const short4_t*)(sm.emb + e);
            short4_t hi = *(const short4_t*)(sm.emb + e + 4);
            short8_t f8;
            f8[0] = lo[0]; f8[1] = lo[1]; f8[2] = lo[2]; f8[3] = lo[3];
            f8[4] = hi[0]; f8[5] = hi[1]; f8[6] = hi[2]; f8[7] = hi[3];
            afrag[tm2][kt] = f8;
        }
    }
    __syncthreads();   // emb dead; keys overlay live

    // ---- init keys (real keys ~ bits(16.0) >> 0) ----
    for (int i = tid; i < NPAD * 3; i += 256) keys[i] = 0u;

    // ---- per-(tm2,r) key offsets: fcol*3 + seg(l), nt-invariant ----
    const int qrow = (lane >> 4) * 4;
    const int fcol = lane & 15;
    int off[2][4];
    #pragma unroll
    for (int tm2 = 0; tm2 < 2; ++tm2) {
        #pragma unroll
        for (int r = 0; r < 4; ++r) {
            int l = wid * 32 + tm2 * 16 + qrow + r;
            int seg = (l >= pool0) + (l >= pool1);
            off[tm2][r] = fcol * 3 + seg;
        }
    }
    // rows 120..127 (invalid) occur only at wid==3, tm2==1, lane>=32
    const bool skip_hi = (wid == 3) && (lane >= 32);
    __syncthreads();

    // ---- main loop: MFMA + 1 ds_max per element (exact f32 max via positive-bit order) ----
    #pragma unroll 3
    for (int nt = 0; nt < NNT; ++nt) {
        const short8_t* bpv = (const short8_t*)(bp) + (nt * NKT) * 64;
        short8_t bfrag[NKT];
        #pragma unroll
        for (int kt = 0; kt < NKT; ++kt) bfrag[kt] = bpv[kt * 64 + lane];

        float4_t acc0 = {0.f, 0.f, 0.f, 0.f};
        float4_t acc1 = {0.f, 0.f, 0.f, 0.f};
        #pragma unroll
        for (int kt = 0; kt < NKT; ++kt) {
            acc0 = __builtin_amdgcn_mfma_f32_16x16x32_bf16(afrag[0][kt], bfrag[kt], acc0, 0, 0, 0);
            acc1 = __builtin_amdgcn_mfma_f32_16x16x32_bf16(afrag[1][kt], bfrag[kt], acc1, 0, 0, 0);
        }

        unsigned* kb = keys + nt * 48;
        #pragma unroll
        for (int r = 0; r < 4; ++r)
            atomicMax(&kb[off[0][r]], __builtin_bit_cast(unsigned, acc0[r] + ACC_BIAS));
        if (!skip_hi) {
            #pragma unroll
            for (int r = 0; r < 4; ++r)
                atomicMax(&kb[off[1][r]], __builtin_bit_cast(unsigned, acc1[r] + ACC_BIAS));
        }
    }
    __syncthreads();

    // ---- decode keys + deferred bias + tanh (690 values) ----
    for (int i = tid; i < FF * 3; i += 256) {
        float m = __builtin_bit_cast(float, keys[i]) - ACC_BIAS;
        int f = i / 3;
        feats[i] = tanh_fast(m + convb[f]);
    }
    __syncthreads();

    // ---- GEMV epilogue (r9 verbatim): wave w covers i in [690w/4, 690(w+1)/4) ----
    {
        int i0 = (690 * wid) >> 2;
        int i1 = (690 * (wid + 1)) >> 2;
        float acc = 0.0f;
        if (lane < 56) {
            #pragma unroll 4
            for (int i = i0; i < i1; ++i)
                acc += feats[i] * linw_t[i * 56 + lane];
            part2[wid * 56 + lane] = acc;
        }
    }
    __syncthreads();
    if (tid < RR) {
        float s = part2[tid] + part2[56 + tid] + part2[112 + tid] + part2[168 + tid];
        out[b * RR + tid] = s + linb[tid];
    }
}

extern "C" void kernel_launch(void* const* d_in, const int* in_sizes, int n_in,
                              void* d_out, int out_size, void* d_ws, size_t ws_size,
                              hipStream_t stream) {
    const int*   sent  = (const int*)d_in[0];
    const int*   pf    = (const int*)d_in[1];
    const int*   epos  = (const int*)d_in[2];
    const float* Wword = (const float*)d_in[3];
    const float* Wpos1 = (const float*)d_in[4];
    const float* Wpos2 = (const float*)d_in[5];
    const float* convw = (const float*)d_in[6];
    const float* convb = (const float*)d_in[7];
    const float* linw  = (const float*)d_in[8];
    const float* linb  = (const float*)d_in[9];
    float* out = (float*)d_out;

    char* ws = (char*)d_ws;
    unsigned short* bp     = (unsigned short*)(ws + WS_BP);
    float*          linw_t = (float*)(ws + WS_LT);
    unsigned short* embg   = (unsigned short*)(ws + WS_EMBG);

    pcnn_prep_b<<<(NNT * NKT * 64 * 8 + 255) / 256, 256, 0, stream>>>(convw, bp);
    pcnn_prep_lt<<<(690 * 56 + 255) / 256, 256, 0, stream>>>(linw, linw_t);
    pcnn_gather<<<(BB * LL * 30) / 256, 256, 0, stream>>>(sent, pf, Wword, Wpos1, Wpos2,
                                                          (unsigned*)embg);
    pcnn_mfma<<<BB, 256, 0, stream>>>(epos, embg, bp, convb, linw_t, linb, out);
}

// Round 12
// 165.565 us; speedup vs baseline: 1.3853x; 1.0055x over previous
//
#include <hip/hip_runtime.h>
#include <math.h>

#define BB 2048
#define LL 120
#define WE_ 50
#define PE_ 5
#define DD 60
#define FF 230
#define KK 3
#define RR 53

#define NKT 6             // K = 192 = 6 x 32
#define NNT 15            // N = 240 = 15 x 16
#define NPAD 240
#define EMB_ELEMS 7936    // LDS row r at elem r*60+4; rows 1..120 live, row 0 & >=121 zero

// workspace layout (bytes)
#define WS_BP    0                        // 46080 bf16 = 92160 B
#define WS_LT    92160                    // linw_t f32 [690][56] = 154560 B
#define WS_EMBG  246784                   // 16-aligned; bf16 [2048][120][60] = 29491200 B

#define ACC_BIAS 16.0f                    // |conv| << 16 -> key positive -> uint bit-order == float order

#define GATHER_ITEMS (BB * LL * 30)       // 7372800, one dword each
#define GATHER_BLKS  (GATHER_ITEMS / 256) // 28800 exact
#define BP_ITEMS     (NNT * NKT * 64 * 8) // 46080
#define LT_ITEMS     (690 * 56)           // 38640
#define PREP_BLKS    ((BP_ITEMS + LT_ITEMS + 255) / 256)

typedef __attribute__((ext_vector_type(8))) short short8_t;
typedef __attribute__((ext_vector_type(4))) short short4_t;
typedef __attribute__((ext_vector_type(4))) float float4_t;

__device__ __forceinline__ unsigned f2bf(float x) {
    unsigned u = __builtin_bit_cast(unsigned, x);
    return (u + 0x7fffu + ((u >> 16) & 1u)) >> 16;
}

__device__ __forceinline__ float tanh_fast(float x) {
    float t = __expf(2.0f * x);
    return 1.0f - 2.0f * __builtin_amdgcn_rcpf(t + 1.0f);
}

// ---- gather (r11 verbatim) + preps merged as tail blocks ----
__global__ __launch_bounds__(256) void pcnn_gp(
    const int* __restrict__ sent, const int* __restrict__ pf,
    const float* __restrict__ Wword, const float* __restrict__ Wpos1,
    const float* __restrict__ Wpos2, const float* __restrict__ convw,
    const float* __restrict__ linw,
    unsigned* __restrict__ embg32, unsigned short* __restrict__ bp,
    float* __restrict__ lt)
{
    int bid = blockIdx.x;
    if (bid < GATHER_BLKS) {
        int idx = bid * 256 + threadIdx.x;             // < 7372800
        int c  = idx % 30;
        int lc = idx / 30;
        int l  = lc % LL;
        int b  = lc / LL;
        unsigned pk;
        if (c < 25) {
            int w = sent[b * LL + l];
            float2 v = *(const float2*)(Wword + w * WE_ + 2 * c);
            pk = f2bf(v.x) | (f2bf(v.y) << 16);
        } else {
            int p = pf[b * 2 * LL + l];
            int q = pf[b * 2 * LL + LL + l];
            int j0 = (c - 25) * 2, j1 = j0 + 1;
            float f0 = (j0 < PE_) ? Wpos1[p * PE_ + j0] : Wpos2[q * PE_ + j0 - PE_];
            float f1 = (j1 < PE_) ? Wpos1[p * PE_ + j1] : Wpos2[q * PE_ + j1 - PE_];
            pk = f2bf(f0) | (f2bf(f1) << 16);
        }
        embg32[idx] = pk;
    } else {
        int idx = (bid - GATHER_BLKS) * 256 + threadIdx.x;
        if (idx < BP_ITEMS) {
            int j    = idx & 7;
            int lane = (idx >> 3) & 63;
            int t    = idx >> 9;
            int kt   = t % NKT;
            int nt   = t / NKT;
            int f    = nt * 16 + (lane & 15);
            int klin = kt * 32 + (lane >> 4) * 8 + j;
            float v = (f < FF && klin < KK * DD) ? convw[f * (KK * DD) + klin] : 0.0f;
            bp[idx] = (unsigned short)f2bf(v);
        } else if (idx < BP_ITEMS + LT_ITEMS) {
            int k = idx - BP_ITEMS;
            int i = k / 56;
            int r = k - i * 56;
            lt[k] = (r < RR) ? linw[r * (3 * FF) + i] : 0.0f;
        }
    }
}

__global__ __launch_bounds__(256) void pcnn_mfma(
    const int* __restrict__ epos,
    const unsigned short* __restrict__ embg,      // [2048][120][60] bf16
    const unsigned short* __restrict__ bp, const float* __restrict__ convb,
    const float* __restrict__ linw_t, const float* __restrict__ linb,
    float* __restrict__ out)
{
    __shared__ __align__(16) union SM {
        unsigned short emb[EMB_ELEMS];                    // 15872 B; row r at elem r*60+4
        float pool[4 * NPAD * 3 + NPAD * 3 + 4 * 56];     // keys | feats | part2
    } sm;
    unsigned* const keys  = (unsigned*)sm.pool;
    float* const feats    = sm.pool + 4 * NPAD * 3;
    float* const part2    = sm.pool + 4 * NPAD * 3 + NPAD * 3;

    const int b    = blockIdx.x;
    const int tid  = threadIdx.x;
    const int wid  = tid >> 6;
    const int lane = tid & 63;

    const int pool0 = epos[b * 2 + 0] + 1;
    const int pool1 = epos[b * 2 + 1] + 1;

    // ---- zero pads as dwords ----
    {
        unsigned* e32 = (unsigned*)sm.emb;
        for (int i = tid; i < 32 + 336; i += 256) {
            int d = (i < 32) ? i : (3600 + i);
            e32[d] = 0u;
        }
    }
    // ---- stage rows 1..120: 900 x 16B, coalesced & aligned ----
    {
        const unsigned short* eb = embg + (size_t)b * (LL * DD);
        #pragma unroll
        for (int k = 0; k < 4; ++k) {
            int c = tid + k * 256;
            if (c < 900) {
                float4 v = *(const float4*)(eb + c * 8);
                *(float4*)((char*)sm.emb + 128 + c * 16) = v;
            }
        }
    }
    __syncthreads();

    // ---- A fragments: wave owns m-tiles {2*wid, 2*wid+1} ----
    short8_t afrag[2][NKT];
    #pragma unroll
    for (int tm2 = 0; tm2 < 2; ++tm2) {
        int l = (2 * wid + tm2) * 16 + (lane & 15);
        #pragma unroll
        for (int kt = 0; kt < NKT; ++kt) {
            int e = l * DD + 4 + kt * 32 + (lane >> 4) * 8;
            short4_t lo = *(const short4_t*)(sm.emb + e);
            short4_t hi = *(const short4_t*)(sm.emb + e + 4);
            short8_t f8;
            f8[0] = lo[0]; f8[1] = lo[1]; f8[2] = lo[2]; f8[3] = lo[3];
            f8[4] = hi[0]; f8[5] = hi[1]; f8[6] = hi[2]; f8[7] = hi[3];
            afrag[tm2][kt] = f8;
        }
    }
    __syncthreads();   // emb dead; keys overlay live

    for (int i = tid; i < NPAD * 3; i += 256) keys[i] = 0u;

    // ---- per-(tm2,r) key offsets + same-seg flags (seg monotone in l) ----
    const int qrow = (lane >> 4) * 4;
    const int fcol = lane & 15;
    int off[2][4];
    #pragma unroll
    for (int tm2 = 0; tm2 < 2; ++tm2) {
        #pragma unroll
        for (int r = 0; r < 4; ++r) {
            int l = wid * 32 + tm2 * 16 + qrow + r;
            int seg = (l >= pool0) + (l >= pool1);
            off[tm2][r] = fcol * 3 + seg;
        }
    }
    const bool same0 = (off[0][0] == off[0][3]);
    const bool same1 = (off[1][0] == off[1][3]);
    // rows 120..127 (invalid) occur only at wid==3, tm2==1, lane>=32
    const bool skip_hi = (wid == 3) && (lane >= 32);
    __syncthreads();

    // ---- main loop: double-buffered B prefetch + MFMA + pooled ds_max ----
    const short8_t* bpv = (const short8_t*)bp;
    short8_t bA[NKT], bB[NKT];
    #pragma unroll
    for (int kt = 0; kt < NKT; ++kt) bA[kt] = bpv[kt * 64 + lane];

    for (int nt = 0; nt < NNT; ++nt) {
        if (nt + 1 < NNT) {                       // issue next tile's loads FIRST
            const short8_t* bn = bpv + (size_t)(nt + 1) * NKT * 64;
            #pragma unroll
            for (int kt = 0; kt < NKT; ++kt) bB[kt] = bn[kt * 64 + lane];
        }

        float4_t acc0 = {0.f, 0.f, 0.f, 0.f};
        float4_t acc1 = {0.f, 0.f, 0.f, 0.f};
        #pragma unroll
        for (int kt = 0; kt < NKT; ++kt) {
            acc0 = __builtin_amdgcn_mfma_f32_16x16x32_bf16(afrag[0][kt], bA[kt], acc0, 0, 0, 0);
            acc1 = __builtin_amdgcn_mfma_f32_16x16x32_bf16(afrag[1][kt], bA[kt], acc1, 0, 0, 0);
        }

        unsigned* kb = keys + nt * 48;
        if (same0) {
            float m = fmaxf(fmaxf(acc0[0], acc0[1]), fmaxf(acc0[2], acc0[3]));
            atomicMax(&kb[off[0][0]], __builtin_bit_cast(unsigned, m + ACC_BIAS));
        } else {
            #pragma unroll
            for (int r = 0; r < 4; ++r)
                atomicMax(&kb[off[0][r]], __builtin_bit_cast(unsigned, acc0[r] + ACC_BIAS));
        }
        if (!skip_hi) {
            if (same1) {
                float m = fmaxf(fmaxf(acc1[0], acc1[1]), fmaxf(acc1[2], acc1[3]));
                atomicMax(&kb[off[1][0]], __builtin_bit_cast(unsigned, m + ACC_BIAS));
            } else {
                #pragma unroll
                for (int r = 0; r < 4; ++r)
                    atomicMax(&kb[off[1][r]], __builtin_bit_cast(unsigned, acc1[r] + ACC_BIAS));
            }
        }

        #pragma unroll
        for (int kt = 0; kt < NKT; ++kt) bA[kt] = bB[kt];
    }
    __syncthreads();

    // ---- decode keys + deferred bias + tanh (690 values) ----
    for (int i = tid; i < FF * 3; i += 256) {
        float m = __builtin_bit_cast(float, keys[i]) - ACC_BIAS;
        int f = i / 3;
        feats[i] = tanh_fast(m + convb[f]);
    }
    __syncthreads();

    // ---- GEMV epilogue: wave w covers i in [690w/4, 690(w+1)/4); coalesced linw_t ----
    {
        int i0 = (690 * wid) >> 2;
        int i1 = (690 * (wid + 1)) >> 2;
        float acc = 0.0f;
        if (lane < 56) {
            #pragma unroll 4
            for (int i = i0; i < i1; ++i)
                acc += feats[i] * linw_t[i * 56 + lane];
            part2[wid * 56 + lane] = acc;
        }
    }
    __syncthreads();
    if (tid < RR) {
        float s = part2[tid] + part2[56 + tid] + part2[112 + tid] + part2[168 + tid];
        out[b * RR + tid] = s + linb[tid];
    }
}

extern "C" void kernel_launch(void* const* d_in, const int* in_sizes, int n_in,
                              void* d_out, int out_size, void* d_ws, size_t ws_size,
                              hipStream_t stream) {
    const int*   sent  = (const int*)d_in[0];
    const int*   pf    = (const int*)d_in[1];
    const int*   epos  = (const int*)d_in[2];
    const float* Wword = (const float*)d_in[3];
    const float* Wpos1 = (const float*)d_in[4];
    const float* Wpos2 = (const float*)d_in[5];
    const float* convw = (const float*)d_in[6];
    const float* convb = (const float*)d_in[7];
    const float* linw  = (const float*)d_in[8];
    const float* linb  = (const float*)d_in[9];
    float* out = (float*)d_out;

    char* ws = (char*)d_ws;
    unsigned short* bp     = (unsigned short*)(ws + WS_BP);
    float*          linw_t = (float*)(ws + WS_LT);
    unsigned short* embg   = (unsigned short*)(ws + WS_EMBG);

    pcnn_gp<<<GATHER_BLKS + PREP_BLKS, 256, 0, stream>>>(
        sent, pf, Wword, Wpos1, Wpos2, convw, linw,
        (unsigned*)embg, bp, linw_t);
    pcnn_mfma<<<BB, 256, 0, stream>>>(epos, embg, bp, convb, linw_t, linb, out);
}

// Round 14
// 158.816 us; speedup vs baseline: 1.4441x; 1.0425x over previous
//
#include <hip/hip_runtime.h>
#include <math.h>

#define BB 2048
#define LL 120
#define WE_ 50
#define PE_ 5
#define DD 60
#define FF 230
#define KK 3
#define RR 53

#define NKT 6             // K = 192 = 6 x 32
#define NNT 15            // N = 240 = 15 x 16
#define NPAD 240
#define EMB_ELEMS 7936    // LDS row r at elem r*60+4; rows 1..120 live, row 0 & >=121 zero

// workspace layout (bytes)
#define WS_BP    0                        // 46080 bf16 = 92160 B
#define WS_LT    92160                    // linw_t f32 [690][56] = 154560 B
#define WS_EMBG  246784                   // bf16 [2048][7200]; per-batch 14400 B (feats f32[690] overlaid after use)

#define ACC_BIAS 16.0f                    // |conv| << 16 -> key positive -> uint bit-order == float order

#define GATHER_ITEMS (BB * LL * 30)       // 7372800, one dword each
#define GATHER_BLKS  (GATHER_ITEMS / 256) // 28800 exact
#define BP_ITEMS     (NNT * NKT * 64 * 8) // 46080
#define LT_ITEMS     (690 * 56)           // 38640
#define PREP_BLKS    ((BP_ITEMS + LT_ITEMS + 255) / 256)

typedef __attribute__((ext_vector_type(8))) short short8_t;
typedef __attribute__((ext_vector_type(4))) short short4_t;
typedef __attribute__((ext_vector_type(4))) float float4_t;

__device__ __forceinline__ unsigned f2bf(float x) {
    unsigned u = __builtin_bit_cast(unsigned, x);
    return (u + 0x7fffu + ((u >> 16) & 1u)) >> 16;
}

__device__ __forceinline__ float tanh_fast(float x) {
    float t = __expf(2.0f * x);
    return 1.0f - 2.0f * __builtin_amdgcn_rcpf(t + 1.0f);
}

// ---- K1: gather + preps (r12 verbatim) ----
__global__ __launch_bounds__(256) void pcnn_gp(
    const int* __restrict__ sent, const int* __restrict__ pf,
    const float* __restrict__ Wword, const float* __restrict__ Wpos1,
    const float* __restrict__ Wpos2, const float* __restrict__ convw,
    const float* __restrict__ linw,
    unsigned* __restrict__ embg32, unsigned short* __restrict__ bp,
    float* __restrict__ lt)
{
    int bid = blockIdx.x;
    if (bid < GATHER_BLKS) {
        int idx = bid * 256 + threadIdx.x;             // < 7372800
        int c  = idx % 30;
        int lc = idx / 30;
        int l  = lc % LL;
        int b  = lc / LL;
        unsigned pk;
        if (c < 25) {
            int w = sent[b * LL + l];
            float2 v = *(const float2*)(Wword + w * WE_ + 2 * c);
            pk = f2bf(v.x) | (f2bf(v.y) << 16);
        } else {
            int p = pf[b * 2 * LL + l];
            int q = pf[b * 2 * LL + LL + l];
            int j0 = (c - 25) * 2, j1 = j0 + 1;
            float f0 = (j0 < PE_) ? Wpos1[p * PE_ + j0] : Wpos2[q * PE_ + j0 - PE_];
            float f1 = (j1 < PE_) ? Wpos1[p * PE_ + j1] : Wpos2[q * PE_ + j1 - PE_];
            pk = f2bf(f0) | (f2bf(f1) << 16);
        }
        embg32[idx] = pk;
    } else {
        int idx = (bid - GATHER_BLKS) * 256 + threadIdx.x;
        if (idx < BP_ITEMS) {
            int j    = idx & 7;
            int lane = (idx >> 3) & 63;
            int t    = idx >> 9;
            int kt   = t % NKT;
            int nt   = t / NKT;
            int f    = nt * 16 + (lane & 15);
            int klin = kt * 32 + (lane >> 4) * 8 + j;
            float v = (f < FF && klin < KK * DD) ? convw[f * (KK * DD) + klin] : 0.0f;
            bp[idx] = (unsigned short)f2bf(v);
        } else if (idx < BP_ITEMS + LT_ITEMS) {
            int k = idx - BP_ITEMS;
            int i = k / 56;
            int r = k - i * 56;
            lt[k] = (r < RR) ? linw[r * (3 * FF) + i] : 0.0f;
        }
    }
}

// ---- K2: conv + pool + tanh; 512 threads, wave-group g does nt [8g, 8g+8) resp [8,15) ----
__global__ __launch_bounds__(512) void pcnn_conv(
    const int* __restrict__ epos,
    unsigned short* __restrict__ embg,            // [2048][7200] bf16; feats overlay per batch
    const unsigned short* __restrict__ bp, const float* __restrict__ convb)
{
    __shared__ __align__(16) union SM {
        unsigned short emb[EMB_ELEMS];            // 15872 B; row r at elem r*60+4
        unsigned keys[NPAD * 3];                  // 2880 B overlay (emb dead)
    } sm;

    const int b    = blockIdx.x;
    const int tid  = threadIdx.x;
    const int wid8 = tid >> 6;
    const int wid4 = wid8 & 3;                    // m-tile owner within group
    const int grp  = wid8 >> 2;                   // 0: nt 0-7, 1: nt 8-14
    const int lane = tid & 63;

    const int pool0 = epos[b * 2 + 0] + 1;
    const int pool1 = epos[b * 2 + 1] + 1;

    // ---- zero pads as dwords ----
    {
        unsigned* e32 = (unsigned*)sm.emb;
        for (int i = tid; i < 32 + 336; i += 512) {
            int d = (i < 32) ? i : (3600 + i);
            e32[d] = 0u;
        }
    }
    // ---- stage rows 1..120: 900 x 16B, coalesced & aligned ----
    {
        const unsigned short* eb = embg + (size_t)b * (LL * DD);
        #pragma unroll
        for (int k = 0; k < 2; ++k) {
            int c = tid + k * 512;
            if (c < 900) {
                float4 v = *(const float4*)(eb + c * 8);
                *(float4*)((char*)sm.emb + 128 + c * 16) = v;
            }
        }
    }
    __syncthreads();

    // ---- A fragments: wave-group member wid4 owns m-tiles {2*wid4, 2*wid4+1} ----
    short8_t afrag[2][NKT];
    #pragma unroll
    for (int tm2 = 0; tm2 < 2; ++tm2) {
        int l = (2 * wid4 + tm2) * 16 + (lane & 15);
        #pragma unroll
        for (int kt = 0; kt < NKT; ++kt) {
            int e = l * DD + 4 + kt * 32 + (lane >> 4) * 8;
            short4_t lo = *(const short4_t*)(sm.emb + e);
            short4_t hi = *(const short4_t*)(sm.emb + e + 4);
            short8_t f8;
            f8[0] = lo[0]; f8[1] = lo[1]; f8[2] = lo[2]; f8[3] = lo[3];
            f8[4] = hi[0]; f8[5] = hi[1]; f8[6] = hi[2]; f8[7] = hi[3];
            afrag[tm2][kt] = f8;
        }
    }
    __syncthreads();   // emb dead; keys overlay live

    for (int i = tid; i < NPAD * 3; i += 512) sm.keys[i] = 0u;

    // ---- per-(tm2,r) key offsets + same-seg flags ----
    const int qrow = (lane >> 4) * 4;
    const int fcol = lane & 15;
    int off[2][4];
    #pragma unroll
    for (int tm2 = 0; tm2 < 2; ++tm2) {
        #pragma unroll
        for (int r = 0; r < 4; ++r) {
            int l = wid4 * 32 + tm2 * 16 + qrow + r;
            int seg = (l >= pool0) + (l >= pool1);
            off[tm2][r] = fcol * 3 + seg;
        }
    }
    const bool same0 = (off[0][0] == off[0][3]);
    const bool same1 = (off[1][0] == off[1][3]);
    const bool skip_hi = (wid4 == 3) && (lane >= 32);   // rows 120..127 invalid
    __syncthreads();

    // ---- nt loop: group 0 -> [0,8), group 1 -> [8,15) ----
    const int nt0 = grp ? 8 : 0;
    const int nt1 = grp ? NNT : 8;
    const short8_t* bpv = (const short8_t*)bp;
    for (int nt = nt0; nt < nt1; ++nt) {
        const short8_t* bn = bpv + (size_t)nt * NKT * 64;
        short8_t bfrag[NKT];
        #pragma unroll
        for (int kt = 0; kt < NKT; ++kt) bfrag[kt] = bn[kt * 64 + lane];

        float4_t acc0 = {0.f, 0.f, 0.f, 0.f};
        float4_t acc1 = {0.f, 0.f, 0.f, 0.f};
        #pragma unroll
        for (int kt = 0; kt < NKT; ++kt) {
            acc0 = __builtin_amdgcn_mfma_f32_16x16x32_bf16(afrag[0][kt], bfrag[kt], acc0, 0, 0, 0);
            acc1 = __builtin_amdgcn_mfma_f32_16x16x32_bf16(afrag[1][kt], bfrag[kt], acc1, 0, 0, 0);
        }

        unsigned* kb = sm.keys + nt * 48;
        if (same0) {
            float m = fmaxf(fmaxf(acc0[0], acc0[1]), fmaxf(acc0[2], acc0[3]));
            atomicMax(&kb[off[0][0]], __builtin_bit_cast(unsigned, m + ACC_BIAS));
        } else {
            #pragma unroll
            for (int r = 0; r < 4; ++r)
                atomicMax(&kb[off[0][r]], __builtin_bit_cast(unsigned, acc0[r] + ACC_BIAS));
        }
        if (!skip_hi) {
            if (same1) {
                float m = fmaxf(fmaxf(acc1[0], acc1[1]), fmaxf(acc1[2], acc1[3]));
                atomicMax(&kb[off[1][0]], __builtin_bit_cast(unsigned, m + ACC_BIAS));
            } else {
                #pragma unroll
                for (int r = 0; r < 4; ++r)
                    atomicMax(&kb[off[1][r]], __builtin_bit_cast(unsigned, acc1[r] + ACC_BIAS));
            }
        }
    }
    __syncthreads();

    // ---- decode keys + deferred bias + tanh -> feats f32[690] into this batch's dead embg region ----
    float* fo = (float*)(embg + (size_t)b * (LL * DD));
    for (int i = tid; i < FF * 3; i += 512) {
        float m = __builtin_bit_cast(float, sm.keys[i]) - ACC_BIAS;
        int f = i / 3;
        fo[i] = tanh_fast(m + convb[f]);
    }
}

// ---- K3: GEMV out[b,:] = feats[b] . linw_t + linb ----
__global__ __launch_bounds__(256) void pcnn_gemv(
    const unsigned short* __restrict__ embg,      // feats overlay at b*14400 B
    const float* __restrict__ linw_t, const float* __restrict__ linb,
    float* __restrict__ out)
{
    __shared__ float feats[FF * 3];
    __shared__ float part2[4 * 56];

    const int b    = blockIdx.x;
    const int tid  = threadIdx.x;
    const int wid  = tid >> 6;
    const int lane = tid & 63;

    const float* fi = (const float*)(embg + (size_t)b * (LL * DD));
    for (int i = tid; i < FF * 3; i += 256) feats[i] = fi[i];
    __syncthreads();

    {
        int i0 = (690 * wid) >> 2;
        int i1 = (690 * (wid + 1)) >> 2;
        float acc = 0.0f;
        if (lane < 56) {
            #pragma unroll 4
            for (int i = i0; i < i1; ++i)
                acc += feats[i] * linw_t[i * 56 + lane];
            part2[wid * 56 + lane] = acc;
        }
    }
    __syncthreads();
    if (tid < RR) {
        float s = part2[tid] + part2[56 + tid] + part2[112 + tid] + part2[168 + tid];
        out[b * RR + tid] = s + linb[tid];
    }
}

extern "C" void kernel_launch(void* const* d_in, const int* in_sizes, int n_in,
                              void* d_out, int out_size, void* d_ws, size_t ws_size,
                              hipStream_t stream) {
    const int*   sent  = (const int*)d_in[0];
    const int*   pf    = (const int*)d_in[1];
    const int*   epos  = (const int*)d_in[2];
    const float* Wword = (const float*)d_in[3];
    const float* Wpos1 = (const float*)d_in[4];
    const float* Wpos2 = (const float*)d_in[5];
    const float* convw = (const float*)d_in[6];
    const float* convb = (const float*)d_in[7];
    const float* linw  = (const float*)d_in[8];
    const float* linb  = (const float*)d_in[9];
    float* out = (float*)d_out;

    char* ws = (char*)d_ws;
    unsigned short* bp     = (unsigned short*)(ws + WS_BP);
    float*          linw_t = (float*)(ws + WS_LT);
    unsigned short* embg   = (unsigned short*)(ws + WS_EMBG);

    pcnn_gp<<<GATHER_BLKS + PREP_BLKS, 256, 0, stream>>>(
        sent, pf, Wword, Wpos1, Wpos2, convw, linw,
        (unsigned*)embg, bp, linw_t);
    pcnn_conv<<<BB, 512, 0, stream>>>(epos, embg, bp, convb);
    pcnn_gemv<<<BB, 256, 0, stream>>>(embg, linw_t, linb, out);
}